// Round 4
// baseline (600.029 us; speedup 1.0000x reference)
//
#include <hip/hip_runtime.h>
#include <math.h>

// Problem constants (B=2, T=2048, D=512, H=8, hd=64, K=16, DEPTH=3)
#define TSEQ   2048
#define DM     512
#define NH     8
#define HD     64
#define KATT   16
#define NDEPTH 3
#define MROWS  4096   // B*T

typedef __attribute__((ext_vector_type(8))) short bf16x8;
typedef __attribute__((ext_vector_type(4))) float f32x4;

// f32 -> bf16 (round-to-nearest-even), bit-level
static __device__ __forceinline__ unsigned short f2b(float f) {
    unsigned int u = __float_as_uint(f);
    unsigned int r = (u + 0x7fffu + ((u >> 16) & 1u)) >> 16;
    return (unsigned short)r;
}

// global -> LDS direct copy, 16 B per lane; HW writes lane i at lds + i*16.
static __device__ __forceinline__ void load_lds16(const void* g, void* l) {
    __builtin_amdgcn_global_load_lds(
        (const __attribute__((address_space(1))) unsigned int*)g,
        (__attribute__((address_space(3))) unsigned int*)l, 16, 0, 0);
}

// ---------------------------------------------------------------------------
// Weight prep: W f32 [K x N] (per depth) -> Wt bf16 [N x K]. grid.z = depth.
// ---------------------------------------------------------------------------
__global__ __launch_bounds__(256) void transpose_w_kernel(
    const float* __restrict__ W, unsigned short* __restrict__ Wt, int Kd, int Nd)
{
    __shared__ float tile[32][33];
    const int n0 = blockIdx.x * 32, k0 = blockIdx.y * 32;
    const size_t off = (size_t)blockIdx.z * Kd * Nd;
    const float* Wd = W + off;
    unsigned short* Wtd = Wt + off;
    const int tx = threadIdx.x, ty = threadIdx.y;
#pragma unroll
    for (int r = 0; r < 32; r += 8)
        tile[ty + r][tx] = Wd[(size_t)(k0 + ty + r) * Nd + (n0 + tx)];
    __syncthreads();
#pragma unroll
    for (int r = 0; r < 32; r += 8)
        Wtd[(size_t)(n0 + ty + r) * Kd + (k0 + tx)] = f2b(tile[tx][ty + r]);
}

// ---------------------------------------------------------------------------
// LayerNorm: x f32 [4096 x 512] -> h bf16 [4096 x 512]. One wave per row.
// ---------------------------------------------------------------------------
__global__ __launch_bounds__(256) void ln_kernel(
    const float* __restrict__ x, const float* __restrict__ sc,
    const float* __restrict__ bi, unsigned short* __restrict__ h)
{
    const int wid  = blockIdx.x * 4 + (threadIdx.x >> 6);
    const int lane = threadIdx.x & 63;
    const float* xr = x + (size_t)wid * DM;
    const float4 v0 = *(const float4*)&xr[lane * 4];
    const float4 v1 = *(const float4*)&xr[256 + lane * 4];
    float s = v0.x + v0.y + v0.z + v0.w + v1.x + v1.y + v1.z + v1.w;
    float q = v0.x*v0.x + v0.y*v0.y + v0.z*v0.z + v0.w*v0.w
            + v1.x*v1.x + v1.y*v1.y + v1.z*v1.z + v1.w*v1.w;
#pragma unroll
    for (int off = 32; off; off >>= 1) {
        s += __shfl_xor(s, off, 64);
        q += __shfl_xor(q, off, 64);
    }
    const float mean = s * (1.0f / DM);
    const float var  = q * (1.0f / DM) - mean * mean;
    const float rs   = rsqrtf(var + 1e-5f);
    unsigned short* hr = h + (size_t)wid * DM;
    const int c0 = lane * 4, c1 = 256 + lane * 4;
    ushort4 o0, o1;
    o0.x = f2b((v0.x - mean) * rs * sc[c0+0] + bi[c0+0]);
    o0.y = f2b((v0.y - mean) * rs * sc[c0+1] + bi[c0+1]);
    o0.z = f2b((v0.z - mean) * rs * sc[c0+2] + bi[c0+2]);
    o0.w = f2b((v0.w - mean) * rs * sc[c0+3] + bi[c0+3]);
    o1.x = f2b((v1.x - mean) * rs * sc[c1+0] + bi[c1+0]);
    o1.y = f2b((v1.y - mean) * rs * sc[c1+1] + bi[c1+1]);
    o1.z = f2b((v1.z - mean) * rs * sc[c1+2] + bi[c1+2]);
    o1.w = f2b((v1.w - mean) * rs * sc[c1+3] + bi[c1+3]);
    *(ushort4*)&hr[c0] = o0;
    *(ushort4*)&hr[c1] = o1;
}

// ---------------------------------------------------------------------------
// Dilated attention, shuffle-free dots (see round-1 notes).
// ---------------------------------------------------------------------------
__global__ __launch_bounds__(256) void attn_kernel(
    const float* __restrict__ qkv, unsigned short* __restrict__ o, int dil)
{
    const int blk  = blockIdx.x;
    const int tile = blk & (TSEQ / 16 - 1);   // 128 query tiles
    const int bh   = blk >> 7;
    const int b    = bh >> 3, hh = bh & 7;
    const int t0   = tile * 16;
    const int wave = threadIdx.x >> 6, lane = threadIdx.x & 63;
    const int tq   = wave * 4 + (lane >> 4);  // query 0..15
    const int s    = lane & 15;               // key slot 0..15
    const int t    = t0 + tq;
    const size_t base = (size_t)b * TSEQ * 1536 + (size_t)hh * HD;

    __shared__ float p_lds[16][17];

    // ---- phase 1: scores + softmax ----
    int row = t - s * dil;
    const bool valid = (row >= 0);
    row = max(row, 0);
    const float* kr = qkv + base + (size_t)row * 1536 + 512;
    const float* qr = qkv + base + (size_t)t * 1536;
    float dot = 0.0f;
#pragma unroll
    for (int j = 0; j < 16; j++) {
        const float4 k4 = *(const float4*)&kr[j * 4];
        const float4 q4 = *(const float4*)&qr[j * 4];
        dot += q4.x * k4.x + q4.y * k4.y + q4.z * k4.z + q4.w * k4.w;
    }
    const float sc = valid ? dot * 0.125f : -1e30f;
    float m = sc;
#pragma unroll
    for (int off = 1; off < 16; off <<= 1) m = fmaxf(m, __shfl_xor(m, off, 64));
    const float p = expf(sc - m);
    float l = p;
#pragma unroll
    for (int off = 1; off < 16; off <<= 1) l += __shfl_xor(l, off, 64);
    p_lds[tq][s] = p / l;
    __syncthreads();

    // ---- phase 2: o = sum_s p * v ----
#pragma unroll
    for (int qi = 0; qi < 4; qi++) {
        const int qq = qi * 4 + wave;
        const int tt = t0 + qq;
        float acc = 0.0f;
#pragma unroll
        for (int ss = 0; ss < KATT; ss++) {
            int vr = tt - ss * dil;
            const float pw = p_lds[qq][ss];   // exactly 0 for masked slots
            vr = max(vr, 0);
            acc += pw * qkv[base + (size_t)vr * 1536 + 1024 + lane];
        }
        o[(size_t)(b * TSEQ + tt) * DM + (size_t)hh * HD + lane] = f2b(acc);
    }
}

// ---------------------------------------------------------------------------
// GEMM: one WAVE per block computing a 64x64 tile (FM=FN=4 -> 16 MFMA per
// 8 ds_read_b128). Parallelism comes from many single-wave blocks per CU
// (8 KB LDS/block -> up to 20 blocks/CU); barrier drains stall only one wave.
//   EPI 0: outf = C                             (qkv)
//   EPI 1: outf = xin + C + bias                (proj, direct)
//   EPI 2: outb = bf16(gelu(C + bias))          (w1, exact gelu)
//   EPI 3: atomicAdd(outf, C [+ xin + bias if z==0])   (w2 split-K)
// LDS layout (forced by global_load_lds lane*16 placement): row-major
// [64 rows x 32 cols], rows 64 B. Within-row k-segment swizzle
// slot = (kseg + (row>>1)) & 3 spreads frag reads over 8 bank groups
// (2-way aliasing = free, m136); without it reads are 8-way conflicted.
// ---------------------------------------------------------------------------
template<int EPI>
__global__ __launch_bounds__(64) void gemm_kernel(
    const unsigned short* __restrict__ A,   // M x K
    const unsigned short* __restrict__ Bt,  // N x K
    const float* __restrict__ bias,         // N (or null)
    const float* __restrict__ xin,          // M x N residual in (or null)
    float* __restrict__ outf,               // f32 out
    unsigned short* __restrict__ outb,      // bf16 out
    int N, int K, int Kslice)
{
    const int bn = blockIdx.x * 64;
    const int bm = blockIdx.y * 64;
    const int lane = threadIdx.x;
    const int ml = lane & 15, quad = lane >> 4;

    __shared__ unsigned short As[64 * 32];
    __shared__ unsigned short Bs[64 * 32];

    f32x4 acc[4][4] = {};

    // staging source: lane i = 4r+s writes LDS row r, byte slot s*16 of its
    // 16-row chunk; source k-segment c chosen so slot = (c + (r>>1)) & 3.
    const int rr = lane >> 2, ss = lane & 3;
    const int cc = ((ss - (rr >> 1)) & 3) * 8;      // shorts
    const int kbeg = blockIdx.z * Kslice;
    const unsigned short* aptr[4];
    const unsigned short* bptr[4];
#pragma unroll
    for (int ch = 0; ch < 4; ch++) {
        aptr[ch] = A  + (size_t)(bm + ch * 16 + rr) * K + kbeg + cc;
        bptr[ch] = Bt + (size_t)(bn + ch * 16 + rr) * K + kbeg + cc;
    }
    // frag read offset: row ml (per 16-row frag), k-segment quad at
    // swizzled slot (quad + (ml>>1)) & 3
    const int fo = ml * 32 + ((quad + (ml >> 1)) & 3) * 8;

    for (int k0 = 0; k0 < Kslice; k0 += 32) {
        __syncthreads();   // previous tile consumed (1-wave: cheap)
#pragma unroll
        for (int ch = 0; ch < 4; ch++) load_lds16(aptr[ch], &As[ch * 512]);
#pragma unroll
        for (int ch = 0; ch < 4; ch++) load_lds16(bptr[ch], &Bs[ch * 512]);
        __syncthreads();   // vmcnt drain: staged data visible
#pragma unroll
        for (int ch = 0; ch < 4; ch++) { aptr[ch] += 32; bptr[ch] += 32; }

        bf16x8 af[4], bf[4];
#pragma unroll
        for (int i = 0; i < 4; i++) af[i] = *(const bf16x8*)&As[i * 512 + fo];
#pragma unroll
        for (int j = 0; j < 4; j++) bf[j] = *(const bf16x8*)&Bs[j * 512 + fo];
#pragma unroll
        for (int i = 0; i < 4; i++)
#pragma unroll
            for (int j = 0; j < 4; j++)
                acc[i][j] = __builtin_amdgcn_mfma_f32_16x16x32_bf16(
                    af[i], bf[j], acc[i][j], 0, 0, 0);
    }

    const bool z0 = (blockIdx.z == 0);
#pragma unroll
    for (int i = 0; i < 4; i++)
#pragma unroll
        for (int j = 0; j < 4; j++)
#pragma unroll
            for (int r = 0; r < 4; r++) {
                const int row = bm + i * 16 + quad * 4 + r;  // C/D: row=quad*4+reg
                const int col = bn + j * 16 + ml;            // C/D: col=lane&15
                const float v = acc[i][j][r];
                const size_t idx = (size_t)row * N + col;
                if (EPI == 0) {
                    outf[idx] = v;
                } else if (EPI == 1) {
                    outf[idx] = xin[idx] + v + bias[col];
                } else if (EPI == 2) {
                    const float u = v + bias[col];
                    const float g = 0.5f * u * (1.0f + erff(u * 0.70710678118654752f));
                    outb[idx] = f2b(g);
                } else {
                    float add = v;
                    if (z0) add += xin[idx] + bias[col];
                    atomicAdd(&outf[idx], add);
                }
            }
}

// ---------------------------------------------------------------------------
extern "C" void kernel_launch(void* const* d_in, const int* in_sizes, int n_in,
                              void* d_out, int out_size, void* d_ws, size_t ws_size,
                              hipStream_t stream)
{
    (void)in_sizes; (void)n_in; (void)out_size; (void)ws_size;
    const float* x_in   = (const float*)d_in[0];
    const float* ln1_s  = (const float*)d_in[1];
    const float* ln1_b  = (const float*)d_in[2];
    const float* qkv_w  = (const float*)d_in[3];
    const float* proj_w = (const float*)d_in[4];
    const float* proj_b = (const float*)d_in[5];
    const float* ln2_s  = (const float*)d_in[6];
    const float* ln2_b  = (const float*)d_in[7];
    const float* w1     = (const float*)d_in[8];
    const float* b1     = (const float*)d_in[9];
    const float* w2     = (const float*)d_in[10];
    const float* b2     = (const float*)d_in[11];

    // Workspace carve-up
    char* ws = (char*)d_ws;
    float*          xbuf = (float*)(ws);                        // 8 MB f32 x
    char*           Q    = ws + 8388608;
    float*          qkvb = (float*)Q;                           // qkv f32 [4096x1536]
    unsigned short* ubuf = (unsigned short*)Q;                  // u bf16 [4096x2048]
    unsigned short* hbuf = (unsigned short*)(ws + 33554432);    // h bf16 [4096x512]
    unsigned short* obuf = (unsigned short*)(ws + 37748736);    // o bf16 [4096x512]
    unsigned short* qkvT = (unsigned short*)(ws + 41943040);    // [3][1536x512]
    unsigned short* projT= (unsigned short*)(ws + 46661632);    // [3][512x512]
    unsigned short* w1T  = (unsigned short*)(ws + 48234496);    // [3][2048x512]
    unsigned short* w2T  = (unsigned short*)(ws + 54525952);    // [3][512x2048]
    float*          x2   = (float*)(ws + 60817408);             // 8 MB f32 ping-pong

    hipMemcpyAsync(xbuf, x_in, (size_t)MROWS * DM * sizeof(float),
                   hipMemcpyDeviceToDevice, stream);

    transpose_w_kernel<<<dim3(1536/32, 512/32, 3),  dim3(32, 8), 0, stream>>>(qkv_w,  qkvT, 512, 1536);
    transpose_w_kernel<<<dim3( 512/32, 512/32, 3),  dim3(32, 8), 0, stream>>>(proj_w, projT, 512, 512);
    transpose_w_kernel<<<dim3(2048/32, 512/32, 3),  dim3(32, 8), 0, stream>>>(w1,     w1T,  512, 2048);
    transpose_w_kernel<<<dim3( 512/32, 2048/32, 3), dim3(32, 8), 0, stream>>>(w2,     w2T, 2048, 512);

    float* xcur = xbuf;
    for (int d = 0; d < NDEPTH; d++) {
        const int dil = 1 << d;
        float* xnext = (d == NDEPTH - 1) ? (float*)d_out : ((d == 0) ? x2 : xbuf);

        // LN1: x -> h (bf16)
        ln_kernel<<<MROWS / 4, 256, 0, stream>>>(xcur, ln1_s + d * DM, ln1_b + d * DM, hbuf);
        // qkv = h @ qkv_w. 24x64 = 1536 single-wave blocks (6/CU).
        gemm_kernel<0><<<dim3(1536/64, MROWS/64), 64, 0, stream>>>(
            hbuf, qkvT + (size_t)d * 1536 * 512, nullptr, nullptr, qkvb, nullptr,
            1536, 512, 512);
        // dilated attention -> o (bf16)
        attn_kernel<<<2 * NH * (TSEQ / 16), 256, 0, stream>>>(qkvb, obuf, dil);
        // x = x + o @ proj_w + proj_b (in-place, direct). 512 blocks.
        gemm_kernel<1><<<dim3(512/64, MROWS/64), 64, 0, stream>>>(
            obuf, projT + (size_t)d * 512 * 512, proj_b + d * DM, xcur, xcur, nullptr,
            512, 512, 512);
        // LN2: x -> h (bf16)
        ln_kernel<<<MROWS / 4, 256, 0, stream>>>(xcur, ln2_s + d * DM, ln2_b + d * DM, hbuf);
        // u = gelu(h @ w1 + b1). 32x64 = 2048 blocks (8/CU).
        gemm_kernel<2><<<dim3(2048/64, MROWS/64), 64, 0, stream>>>(
            hbuf, w1T + (size_t)d * 2048 * 512, b1 + d * 2048, nullptr, nullptr, ubuf,
            2048, 512, 512);
        // x_next = x + u @ w2 + b2, split-K x4 via atomics. 8x64x4 = 2048 blocks.
        hipMemsetAsync(xnext, 0, (size_t)MROWS * DM * sizeof(float), stream);
        gemm_kernel<3><<<dim3(512/64, MROWS/64, 4), 64, 0, stream>>>(
            ubuf, w2T + (size_t)d * 512 * 2048, b2 + d * DM, xcur, xnext, nullptr,
            512, 2048, 512);
        xcur = xnext;
    }
}